// Round 5
// baseline (311.475 us; speedup 1.0000x reference)
//
#include <hip/hip_runtime.h>

// PointPillarsScatter: out[b][c][y][x] = feat[m][c] for the LAST point m
// (numpy last-write-wins) with coords (b, _, y, x); 0 elsewhere.
//
// Pass 1: winner[slot] = atomicMax(m+1)  (0 = empty; max m == last write wins)
// Pass 2: gather; each thread owns 4 consecutive x of one (b,y) and a
//         16-channel group. Output is write-once/never-read -> NON-TEMPORAL
//         stores (bypass L2 allocation; keep L2 for winner/feat reads).
//         Read-once feat rows use non-temporal loads.
// NOTE: __builtin_nontemporal_* rejects HIP_vector_type structs (float4);
//       use clang ext_vector_type instead.

#define NXc 512
#define NYc 512
#define Cc  64
#define CG  16   // channels per thread

typedef float f32x4 __attribute__((ext_vector_type(4)));
typedef int   i32x4 __attribute__((ext_vector_type(4)));

__global__ void __launch_bounds__(256)
winners_kernel(const int* __restrict__ coords, int* __restrict__ winner, int M) {
    int m = blockIdx.x * blockDim.x + threadIdx.x;
    if (m >= M) return;
    i32x4 cd = __builtin_nontemporal_load((const i32x4*)coords + m);  // [b,z,y,x]
    int slot = cd.x * (NYc * NXc) + cd.z * NXc + cd.w;
    atomicMax(&winner[slot], m + 1);             // 0 stays "empty"
}

__global__ void __launch_bounds__(256)
gather_kernel(const float* __restrict__ feat, const int* __restrict__ winner,
              float* __restrict__ out) {
    int tid = blockIdx.x * blockDim.x + threadIdx.x;   // 0 .. B*NY*NX/4-1
    int x4 = (tid & (NXc / 4 - 1)) * 4;                // 0..508 step 4
    int by = tid >> 7;                                 // NX/4 = 128
    int y  = by & (NYc - 1);
    int b  = by >> 9;
    int c0 = blockIdx.y * CG;                          // channel group base
    const int plane = NYc * NXc;                       // 262144

    i32x4 w = *(const i32x4*)(winner + b * plane + y * NXc + x4);

    f32x4 z4 = {0.f, 0.f, 0.f, 0.f};
    f32x4 r0[CG / 4], r1[CG / 4], r2[CG / 4], r3[CG / 4];
    #pragma unroll
    for (int j = 0; j < CG / 4; ++j) { r0[j] = z4; r1[j] = z4; r2[j] = z4; r3[j] = z4; }

    if (w.x > 0) { const f32x4* p = (const f32x4*)(feat + (size_t)(w.x - 1) * Cc + c0);
        #pragma unroll
        for (int j = 0; j < CG / 4; ++j) r0[j] = __builtin_nontemporal_load(p + j); }
    if (w.y > 0) { const f32x4* p = (const f32x4*)(feat + (size_t)(w.y - 1) * Cc + c0);
        #pragma unroll
        for (int j = 0; j < CG / 4; ++j) r1[j] = __builtin_nontemporal_load(p + j); }
    if (w.z > 0) { const f32x4* p = (const f32x4*)(feat + (size_t)(w.z - 1) * Cc + c0);
        #pragma unroll
        for (int j = 0; j < CG / 4; ++j) r2[j] = __builtin_nontemporal_load(p + j); }
    if (w.w > 0) { const f32x4* p = (const f32x4*)(feat + (size_t)(w.w - 1) * Cc + c0);
        #pragma unroll
        for (int j = 0; j < CG / 4; ++j) r3[j] = __builtin_nontemporal_load(p + j); }

    float* obase = out + (size_t)(b * Cc + c0) * plane + y * NXc + x4;

    #pragma unroll
    for (int j = 0; j < CG / 4; ++j) {
        f32x4 o;
        o = (f32x4){r0[j].x, r1[j].x, r2[j].x, r3[j].x};
        __builtin_nontemporal_store(o, (f32x4*)(obase + (size_t)(j * 4 + 0) * plane));
        o = (f32x4){r0[j].y, r1[j].y, r2[j].y, r3[j].y};
        __builtin_nontemporal_store(o, (f32x4*)(obase + (size_t)(j * 4 + 1) * plane));
        o = (f32x4){r0[j].z, r1[j].z, r2[j].z, r3[j].z};
        __builtin_nontemporal_store(o, (f32x4*)(obase + (size_t)(j * 4 + 2) * plane));
        o = (f32x4){r0[j].w, r1[j].w, r2[j].w, r3[j].w};
        __builtin_nontemporal_store(o, (f32x4*)(obase + (size_t)(j * 4 + 3) * plane));
    }
}

extern "C" void kernel_launch(void* const* d_in, const int* in_sizes, int n_in,
                              void* d_out, int out_size, void* d_ws, size_t ws_size,
                              hipStream_t stream) {
    const float* feat   = (const float*)d_in[0];
    const int*   coords = (const int*)d_in[1];
    float*       out    = (float*)d_out;

    const int M = in_sizes[1] / 4;                 // coordinates is (M,4)
    const int B = out_size / (Cc * NYc * NXc);     // 4

    int* winner = (int*)d_ws;                      // B*NY*NX ints = 4 MiB
    const size_t wbytes = (size_t)B * NYc * NXc * sizeof(int);

    // winner = 0 (empty). ws is re-poisoned to 0xAA each call -> must re-init.
    (void)hipMemsetAsync(winner, 0, wbytes, stream);

    winners_kernel<<<(M + 255) / 256, 256, 0, stream>>>(coords, winner, M);

    dim3 grid(B * NYc * NXc / 4 / 256, Cc / CG);   // (1024, 4)
    gather_kernel<<<grid, 256, 0, stream>>>(feat, winner, out);
}